// Round 1
// baseline (896.316 us; speedup 1.0000x reference)
//
#include <hip/hip_runtime.h>
#include <stdint.h>

#define T_TOK 1024
#define HD 2880
#define ID 2880
#define NE 16
#define NTOP 4

#define BM 128
#define BN 64
#define BK 64
#define NKT (HD / BK)   // 45

typedef short bf16x8 __attribute__((ext_vector_type(8)));
typedef float f32x4 __attribute__((ext_vector_type(4)));

__device__ __forceinline__ unsigned short f2bf(float f) {
    union { float f; uint32_t u; } a; a.f = f;
    return (unsigned short)((a.u + 0x7FFFu + ((a.u >> 16) & 1u)) >> 16);
}

__device__ __forceinline__ uint4 pack8(const float* v) {
    union { unsigned short s[8]; uint4 q; } p;
#pragma unroll
    for (int j = 0; j < 8; j++) p.s[j] = f2bf(v[j]);
    return p.q;
}

// ---------------- init: zero output + counts ----------------
__global__ __launch_bounds__(256) void k_init(float* __restrict__ out, int* __restrict__ cnt) {
    int i = blockIdx.x * 256 + threadIdx.x;
    ((float4*)out)[i] = make_float4(0.f, 0.f, 0.f, 0.f);
    if (blockIdx.x == 0 && threadIdx.x < NE) cnt[threadIdx.x] = 0;
}

// ---------------- router: logits, softmax, top-4, build lists ----------------
__global__ __launch_bounds__(256) void k_router(
    const float* __restrict__ x, const float* __restrict__ rw, const float* __restrict__ rb,
    float* __restrict__ topw, int* __restrict__ cnt, int* __restrict__ list)
{
    const int t = blockIdx.x;
    const int tid = threadIdx.x;
    float acc[NE];
#pragma unroll
    for (int e = 0; e < NE; e++) acc[e] = 0.f;
    for (int c = tid; c < HD; c += 256) {
        float xv = x[(size_t)t * HD + c];
#pragma unroll
        for (int e = 0; e < NE; e++) acc[e] += xv * rw[(size_t)e * HD + c];
    }
    __shared__ float red[4][NE];
    const int lane = tid & 63, wv = tid >> 6;
#pragma unroll
    for (int e = 0; e < NE; e++) {
        float v = acc[e];
#pragma unroll
        for (int off = 32; off > 0; off >>= 1) v += __shfl_down(v, off, 64);
        if (lane == 0) red[wv][e] = v;
    }
    __syncthreads();
    if (tid == 0) {
        float p[NE];
        float mx = -1e30f;
        for (int e = 0; e < NE; e++) {
            float v = red[0][e] + red[1][e] + red[2][e] + red[3][e] + rb[e];
            p[e] = v; mx = fmaxf(mx, v);
        }
        for (int e = 0; e < NE; e++) p[e] = expf(p[e] - mx);  // unnormalized probs
        int sel[NTOP]; float pw[NTOP]; float ssum = 0.f;
        for (int k = 0; k < NTOP; k++) {
            float best = -1.f; int bi = 0;
            for (int e = 0; e < NE; e++)
                if (p[e] > best) { best = p[e]; bi = e; }   // strict > : first index wins ties
            sel[k] = bi; pw[k] = best; ssum += best; p[bi] = -2.f;
        }
        for (int k = 0; k < NTOP; k++) {
            topw[t * NTOP + k] = pw[k] / ssum;              // renormalized combine weight
            int e = sel[k];
            int pos = atomicAdd(&cnt[e], 1);
            list[e * T_TOK + pos] = t * NTOP + k;
        }
    }
}

// ---------------- prefix scan of counts ----------------
__global__ void k_scan(const int* __restrict__ cnt, int* __restrict__ offs) {
    if (threadIdx.x == 0 && blockIdx.x == 0) {
        int s = 0;
        for (int e = 0; e < NE; e++) { offs[e] = s; s += cnt[e]; }
        offs[NE] = s;
    }
}

// ---------------- GEMM1: act = swiglu(x@wg + bg, x@wu + bu)  (bf16 out) ----------------
__global__ __launch_bounds__(512) void k_gemm1(
    const float* __restrict__ x,
    const float* __restrict__ wg, const float* __restrict__ bg,
    const float* __restrict__ wu, const float* __restrict__ bu,
    const int* __restrict__ cnt, const int* __restrict__ offs,
    const int* __restrict__ list,
    unsigned short* __restrict__ act)
{
    const int e = blockIdx.z;
    const int count = cnt[e];
    const int m0 = blockIdx.y * BM;
    if (m0 >= count) return;
    const int mcount = min(BM, count - m0);
    const int i0 = blockIdx.x * BN;
    const int tid = threadIdx.x;

    __shared__ uint4 sAq[BM * BK * 2 / 16];
    __shared__ uint4 sGq[BN * BK * 2 / 16];
    __shared__ uint4 sUq[BN * BK * 2 / 16];
    __shared__ int lidx[BM];
    char* sA = (char*)sAq; char* sG = (char*)sGq; char* sU = (char*)sUq;

    if (tid < BM) lidx[tid] = list[e * T_TOK + m0 + min(tid, mcount - 1)];
    __syncthreads();

    // A staging map: 4 threads per row, 16 floats each
    const int ar = tid >> 2, acg = tid & 3;
    const int tok = lidx[ar] >> 2;
    const float* asrc = x + (size_t)tok * HD + acg * 16;

    // W staging map: tid<256 -> gate, tid>=256 -> up. 64 i-cols x 4 h-groups of 16
    const int wtid = tid & 255;
    const int wc = wtid & 63, whg = wtid >> 6;
    const float* wbase = (tid < 256 ? wg : wu) + ((size_t)e * HD + whg * 16) * ID + i0 + wc;
    char* wdst = (tid < 256 ? sG : sU);

    const int lane = tid & 63, wid = tid >> 6;
    const int wm = wid >> 1, wn = wid & 1;
    const int lr = lane & 15, lk = lane >> 4;

    f32x4 accG[2][2], accU[2][2];
#pragma unroll
    for (int mb = 0; mb < 2; mb++)
#pragma unroll
        for (int cb = 0; cb < 2; cb++) {
            accG[mb][cb] = (f32x4){0.f, 0.f, 0.f, 0.f};
            accU[mb][cb] = (f32x4){0.f, 0.f, 0.f, 0.f};
        }

    for (int kt = 0; kt < NKT; kt++) {
        const int h0 = kt * BK;
        {   // stage A (fp32 -> bf16)
            const float* s = asrc + h0;
            float v[16];
#pragma unroll
            for (int p = 0; p < 4; p++) {
                float4 f = ((const float4*)s)[p];
                v[p * 4 + 0] = f.x; v[p * 4 + 1] = f.y; v[p * 4 + 2] = f.z; v[p * 4 + 3] = f.w;
            }
            *(uint4*)(sA + ar * 128 + (((acg * 2) ^ (ar & 7)) * 16)) = pack8(v);
            *(uint4*)(sA + ar * 128 + (((acg * 2 + 1) ^ (ar & 7)) * 16)) = pack8(v + 8);
        }
        {   // stage W transposed: sW[i][k] (fp32 -> bf16), coalesced column reads
            const float* s = wbase + (size_t)h0 * ID;
            float v[16];
#pragma unroll
            for (int j = 0; j < 16; j++) v[j] = s[(size_t)j * ID];
            *(uint4*)(wdst + wc * 128 + (((whg * 2) ^ (wc & 7)) * 16)) = pack8(v);
            *(uint4*)(wdst + wc * 128 + (((whg * 2 + 1) ^ (wc & 7)) * 16)) = pack8(v + 8);
        }
        __syncthreads();
#pragma unroll
        for (int ks = 0; ks < 2; ks++) {
            const int s = ks * 4 + lk;
            bf16x8 af[2], gf[2], uf[2];
#pragma unroll
            for (int mb = 0; mb < 2; mb++) {
                int rr = wm * 32 + mb * 16 + lr;
                af[mb] = *(const bf16x8*)(sA + rr * 128 + ((s ^ (rr & 7)) * 16));
            }
#pragma unroll
            for (int cb = 0; cb < 2; cb++) {
                int ii = wn * 32 + cb * 16 + lr;
                gf[cb] = *(const bf16x8*)(sG + ii * 128 + ((s ^ (ii & 7)) * 16));
                uf[cb] = *(const bf16x8*)(sU + ii * 128 + ((s ^ (ii & 7)) * 16));
            }
#pragma unroll
            for (int mb = 0; mb < 2; mb++)
#pragma unroll
                for (int cb = 0; cb < 2; cb++) {
                    accG[mb][cb] = __builtin_amdgcn_mfma_f32_16x16x32_bf16(af[mb], gf[cb], accG[mb][cb], 0, 0, 0);
                    accU[mb][cb] = __builtin_amdgcn_mfma_f32_16x16x32_bf16(af[mb], uf[cb], accU[mb][cb], 0, 0, 0);
                }
        }
        __syncthreads();
    }

    const int gbase = offs[e] + m0;
#pragma unroll
    for (int mb = 0; mb < 2; mb++)
#pragma unroll
        for (int cb = 0; cb < 2; cb++) {
            const int col = i0 + wn * 32 + cb * 16 + lr;
            const float bgv = bg[e * ID + col];
            const float buv = bu[e * ID + col];
#pragma unroll
            for (int q = 0; q < 4; q++) {
                const int r = wm * 32 + mb * 16 + lk * 4 + q;
                if (r < mcount) {
                    float gv = fminf(accG[mb][cb][q] + bgv, 7.0f);
                    float uv = fminf(fmaxf(accU[mb][cb][q] + buv, -7.0f), 7.0f);
                    float av = (uv + 1.0f) * (gv / (1.0f + __expf(-1.702f * gv)));
                    act[(size_t)(gbase + r) * ID + col] = f2bf(av);
                }
            }
        }
}

// ---------------- GEMM2: out[t] += w * (act@wd + bd) ----------------
__global__ __launch_bounds__(512) void k_gemm2(
    const unsigned short* __restrict__ act,
    const float* __restrict__ wd, const float* __restrict__ bd,
    const float* __restrict__ topw,
    const int* __restrict__ cnt, const int* __restrict__ offs,
    const int* __restrict__ list,
    float* __restrict__ out)
{
    const int e = blockIdx.z;
    const int count = cnt[e];
    const int m0 = blockIdx.y * BM;
    if (m0 >= count) return;
    const int mcount = min(BM, count - m0);
    const int h0 = blockIdx.x * BN;
    const int tid = threadIdx.x;
    const int gbase = offs[e] + m0;

    __shared__ uint4 sAq[BM * BK * 2 / 16];
    __shared__ uint4 sWq[BN * BK * 2 / 16];
    __shared__ int lidx[BM];
    char* sA = (char*)sAq; char* sW = (char*)sWq;

    if (tid < BM) lidx[tid] = list[e * T_TOK + m0 + min(tid, mcount - 1)];
    __syncthreads();

    const int ar = tid >> 2, acg = tid & 3;
    const int arow = gbase + min(ar, mcount - 1);   // clamp: stay inside valid act rows
    const unsigned short* asrc = act + (size_t)arow * ID + acg * 16;

    const int wc = tid & 63, whg = tid >> 6;        // 0..7 k-groups of 8
    const float* wbase = wd + (size_t)e * ID * HD + (size_t)(whg * 8) * HD + h0 + wc;

    const int lane = tid & 63, wid = tid >> 6;
    const int wm = wid >> 1, wn = wid & 1;
    const int lr = lane & 15, lk = lane >> 4;

    f32x4 acc[2][2];
#pragma unroll
    for (int mb = 0; mb < 2; mb++)
#pragma unroll
        for (int cb = 0; cb < 2; cb++) acc[mb][cb] = (f32x4){0.f, 0.f, 0.f, 0.f};

    for (int kt = 0; kt < NKT; kt++) {
        const int k0 = kt * BK;
        {   // stage A (already bf16): straight 32B copy
            const uint4* s = (const uint4*)(asrc + k0);
            *(uint4*)(sA + ar * 128 + (((acg * 2) ^ (ar & 7)) * 16)) = s[0];
            *(uint4*)(sA + ar * 128 + (((acg * 2 + 1) ^ (ar & 7)) * 16)) = s[1];
        }
        {   // stage W transposed (fp32 -> bf16)
            const float* s = wbase + (size_t)k0 * HD;
            float v[8];
#pragma unroll
            for (int j = 0; j < 8; j++) v[j] = s[(size_t)j * HD];
            *(uint4*)(sW + wc * 128 + ((whg ^ (wc & 7)) * 16)) = pack8(v);
        }
        __syncthreads();
#pragma unroll
        for (int ks = 0; ks < 2; ks++) {
            const int s = ks * 4 + lk;
            bf16x8 af[2], wf[2];
#pragma unroll
            for (int mb = 0; mb < 2; mb++) {
                int rr = wm * 32 + mb * 16 + lr;
                af[mb] = *(const bf16x8*)(sA + rr * 128 + ((s ^ (rr & 7)) * 16));
            }
#pragma unroll
            for (int cb = 0; cb < 2; cb++) {
                int ii = wn * 32 + cb * 16 + lr;
                wf[cb] = *(const bf16x8*)(sW + ii * 128 + ((s ^ (ii & 7)) * 16));
            }
#pragma unroll
            for (int mb = 0; mb < 2; mb++)
#pragma unroll
                for (int cb = 0; cb < 2; cb++)
                    acc[mb][cb] = __builtin_amdgcn_mfma_f32_16x16x32_bf16(af[mb], wf[cb], acc[mb][cb], 0, 0, 0);
        }
        __syncthreads();
    }

#pragma unroll
    for (int mb = 0; mb < 2; mb++)
#pragma unroll
        for (int cb = 0; cb < 2; cb++) {
            const int col = h0 + wn * 32 + cb * 16 + lr;
            const float bdv = bd[e * HD + col];
#pragma unroll
            for (int q = 0; q < 4; q++) {
                const int r = wm * 32 + mb * 16 + lk * 4 + q;
                if (r < mcount) {
                    int idx = lidx[r];
                    float w = topw[idx];
                    atomicAdd(&out[(size_t)(idx >> 2) * HD + col], w * (acc[mb][cb][q] + bdv));
                }
            }
        }
}

extern "C" void kernel_launch(void* const* d_in, const int* in_sizes, int n_in,
                              void* d_out, int out_size, void* d_ws, size_t ws_size,
                              hipStream_t stream)
{
    const float* x  = (const float*)d_in[0];
    const float* rw = (const float*)d_in[1];
    const float* rb = (const float*)d_in[2];
    const float* wg = (const float*)d_in[3];
    const float* bg = (const float*)d_in[4];
    const float* wu = (const float*)d_in[5];
    const float* bu = (const float*)d_in[6];
    const float* wd = (const float*)d_in[7];
    const float* bd = (const float*)d_in[8];
    float* out = (float*)d_out;

    char* ws = (char*)d_ws;
    int*   cnt  = (int*)(ws + 0);            // 16 ints
    int*   offs = (int*)(ws + 256);          // 17 ints
    float* topw = (float*)(ws + 1024);       // T*4 floats
    int*   list = (int*)(ws + 32768);        // E*T ints
    unsigned short* act = (unsigned short*)(ws + 131072); // 4096 x 2880 bf16 (23.6 MB)

    hipLaunchKernelGGL(k_init, dim3(T_TOK * HD / 1024), dim3(256), 0, stream, out, cnt);
    hipLaunchKernelGGL(k_router, dim3(T_TOK), dim3(256), 0, stream, x, rw, rb, topw, cnt, list);
    hipLaunchKernelGGL(k_scan, dim3(1), dim3(64), 0, stream, cnt, offs);
    hipLaunchKernelGGL(k_gemm1, dim3(ID / BN, T_TOK / BM, NE), dim3(512), 0, stream,
                       x, wg, bg, wu, bu, cnt, offs, list, act);
    hipLaunchKernelGGL(k_gemm2, dim3(HD / BN, T_TOK / BM, NE), dim3(512), 0, stream,
                       act, wd, bd, topw, cnt, offs, list, out);
}